// Round 18
// baseline (380.970 us; speedup 1.0000x reference)
//
#include <hip/hip_runtime.h>
#include <hip/hip_bf16.h>

#define NE 8
#define HD 256
#define NT 128
#define NTHREADS 256
#define WPITCH 40                      // 32 k + 8 pad elems; 80 B rows (16B-aligned)
#define SLICE_ELEMS (HD * WPITCH)      // 10240 elems = 20480 B per K-slice

typedef __attribute__((ext_vector_type(8))) short short8;
typedef __attribute__((ext_vector_type(4))) float f32x4;

__device__ __forceinline__ unsigned short f2bf_u16(float f) {
    union { __hip_bfloat16 b; unsigned short u; } v;
    v.b = __float2bfloat16(f);          // HW RNE convert
    return v.u;
}
__device__ __forceinline__ unsigned int pack2bf(float lo, float hi) {
    return (unsigned int)f2bf_u16(lo) | ((unsigned int)f2bf_u16(hi) << 16);
}
// Act LDS swizzle (element units), proven in R12/R17.
__device__ __forceinline__ int swz(int row, int col) {
    return row * HD + (col ^ ((row & 7) << 3));
}

// Weights pre-swizzled: Wp[e][slice s][n][WPITCH], [n][0..31] = W[k=s*32+kk][n].
// Linear global_load_lds staging reproduces this layout in LDS verbatim.
__global__ void prep_weights(const float* __restrict__ W1, const float* __restrict__ W2,
                             unsigned short* __restrict__ W1p, unsigned short* __restrict__ W2p) {
    int idx = blockIdx.x * blockDim.x + threadIdx.x;
    const int TOT = NE * 8 * SLICE_ELEMS;
    if (idx >= TOT) return;
    int kk = idx % WPITCH;
    int n  = (idx / WPITCH) % HD;
    int s  = (idx / (WPITCH * HD)) % 8;
    int e  = idx / (WPITCH * HD * 8);
    float v1 = 0.f, v2 = 0.f;
    if (kk < 32) {
        int k = s * 32 + kk;
        v1 = W1[(e * HD + k) * HD + n];
        v2 = W2[(e * HD + k) * HD + n];
    }
    W1p[idx] = f2bf_u16(v1);
    W2p[idx] = f2bf_u16(v2);
}

// Async stage one K-slice QUARTER: wave w covers bytes [w*5120, w*5120+5120)
// = weight rows [w*64, w*64+64) — exactly the rows wave w later reads.
// Completion guaranteed by the per-slice __syncthreads (full vmcnt drain).
__device__ __forceinline__ void stage_slice(const unsigned short* __restrict__ gsrc,
                                            unsigned short* lbase, int w, int lane) {
    const char* g = (const char*)gsrc + w * 5120 + lane * 16;
    char* l = (char*)lbase + w * 5120;
    #pragma unroll
    for (int i = 0; i < 5; ++i)
        __builtin_amdgcn_global_load_lds(
            (const __attribute__((address_space(1))) unsigned int*)(g + i * 1024),
            (__attribute__((address_space(3))) unsigned int*)(l + i * 1024),
            16, 0, 0);
}

// One K-slice: 4 af (LDS, own staged rows) x 8 bf (LDS Act) -> 32 MFMA.
#define KSLICE_BODY(CURBUF)                                                                  \
    {                                                                                        \
        const unsigned short* Ar = (CURBUF) + (w*64 + l15) * WPITCH + kg*8;                  \
        short8 af0 = *(const short8*)(Ar + 0*16*WPITCH);                                     \
        short8 af1 = *(const short8*)(Ar + 1*16*WPITCH);                                     \
        short8 af2 = *(const short8*)(Ar + 2*16*WPITCH);                                     \
        short8 af3 = *(const short8*)(Ar + 3*16*WPITCH);                                     \
        const int k0 = s*32 + kg*8;                                                          \
        _Pragma("unroll")                                                                    \
        for (int nt = 0; nt < 8; ++nt) {                                                     \
            short8 bf = *(const short8*)(Act + swz(nt*16 + l15, k0));                        \
            acc[0][nt] = __builtin_amdgcn_mfma_f32_16x16x32_bf16(af0, bf, acc[0][nt], 0,0,0);\
            acc[1][nt] = __builtin_amdgcn_mfma_f32_16x16x32_bf16(af1, bf, acc[1][nt], 0,0,0);\
            acc[2][nt] = __builtin_amdgcn_mfma_f32_16x16x32_bf16(af2, bf, acc[2][nt], 0,0,0);\
            acc[3][nt] = __builtin_amdgcn_mfma_f32_16x16x32_bf16(af3, bf, acc[3][nt], 0,0,0);\
        }                                                                                    \
    }

// One expert per block: blockIdx = tile*8 + e (expert<->XCD affinity).
// m97-style schedule: stage(next) -> compute(cur) -> __syncthreads per slice.
__global__ __launch_bounds__(NTHREADS, 2) void moe_expert(
    const float* __restrict__ coords, int npts,
    const float* __restrict__ W0, const float* __restrict__ b0,
    const unsigned short* __restrict__ W1p, const float* __restrict__ b1,
    const unsigned short* __restrict__ W2p, const float* __restrict__ b2,
    const float* __restrict__ W3, const float* __restrict__ b3,
    float* __restrict__ ws)
{
    __shared__ __align__(16) unsigned short Act[NT * HD];      // 64 KB
    __shared__ __align__(16) unsigned short WbA[SLICE_ELEMS];  // 20 KB
    __shared__ __align__(16) unsigned short WbB[SLICE_ELEMS];  // 20 KB
    __shared__ float cbuf[NT * 3];                             // 1.5 KB
    __shared__ float pscr[NT * 4];                             // 2 KB

    const int t = threadIdx.x;
    const int lane = t & 63;
    const int w = t >> 6;       // 0..3: neuron group of 64
    const int l15 = lane & 15;
    const int kg = lane >> 4;
    const int e = blockIdx.x & 7;
    const int p0 = (blockIdx.x >> 3) * NT;

    const unsigned short* W1e = W1p + e * 8 * SLICE_ELEMS;
    const unsigned short* W2e = W2p + e * 8 * SLICE_ELEMS;

    if (t < NT * 3 - 256) { /* nothing: NT*3=384 > 256, loop below */ }
    for (int i = t; i < NT * 3; i += NTHREADS) {
        int idx = p0 * 3 + i;
        int lim = npts * 3 - 1;
        cbuf[i] = coords[idx < lim ? idx : lim];   // clamp; store masked later
    }
    const int j2 = (t & 127) * 2;            // 2 consecutive neurons
    const int prow0 = (t >> 7) * 64;         // 64 points per half
    const float wx0 = W0[(e*3+0)*HD + j2], wx1 = W0[(e*3+0)*HD + j2+1];
    const float wy0 = W0[(e*3+1)*HD + j2], wy1 = W0[(e*3+1)*HD + j2+1];
    const float wz0 = W0[(e*3+2)*HD + j2], wz1 = W0[(e*3+2)*HD + j2+1];
    const float bb0 = b0[e*HD + j2],       bb1 = b0[e*HD + j2+1];
    f32x4 b1v[4];
    #pragma unroll
    for (int mt = 0; mt < 4; ++mt)
        b1v[mt] = *(const f32x4*)(b1 + e*HD + w*64 + mt*16 + kg*4);
    __syncthreads();                    // cbuf visible

    // ---- kick off layer-1 slice 0 staging; hidden under L0 compute ----
    stage_slice(W1e, WbA, w, lane);

    // ---- layer 0: 3 -> 256, fp32 VALU, packed writes into Act ----
    #pragma unroll 4
    for (int pp = 0; pp < 64; ++pp) {
        int p = prow0 + pp;
        float x = cbuf[p*3], y = cbuf[p*3+1], z = cbuf[p*3+2];
        float h0 = fmaxf(x*wx0 + y*wy0 + z*wz0 + bb0, 0.f);
        float h1 = fmaxf(x*wx1 + y*wy1 + z*wz1 + bb1, 0.f);
        *(unsigned int*)(Act + swz(p, j2)) = pack2bf(h0, h1);
    }
    __syncthreads();                    // Act ready + slice-0 staging drained

    f32x4 acc[4][8];
    #pragma unroll
    for (int mt = 0; mt < 4; ++mt)
        #pragma unroll
        for (int nt = 0; nt < 8; ++nt)
            acc[mt][nt] = (f32x4){0.f, 0.f, 0.f, 0.f};

    // ---- layer 1: 8 K-slices, double-buffered; one __syncthreads per slice ----
    #pragma unroll
    for (int s = 0; s < 8; ++s) {
        unsigned short* cur = (s & 1) ? WbB : WbA;
        unsigned short* nxt = (s & 1) ? WbA : WbB;
        if (s < 7) stage_slice(W1e + (s+1) * SLICE_ELEMS, nxt, w, lane);
        else       stage_slice(W2e, nxt, w, lane);          // chain layer-2 s0
        KSLICE_BODY(cur)
        __syncthreads();                // drains DMA (nxt ready) + fence
    }

    // ---- layer-1 epilogue: bias+relu -> Act in place ----
    #pragma unroll
    for (int mt = 0; mt < 4; ++mt) {
        const int n0 = w*64 + mt*16 + kg*4;
        const f32x4 bb = b1v[mt];
        #pragma unroll
        for (int nt = 0; nt < 8; ++nt) {
            const int p = nt*16 + l15;
            unsigned int lo = pack2bf(fmaxf(acc[mt][nt][0] + bb[0], 0.f),
                                      fmaxf(acc[mt][nt][1] + bb[1], 0.f));
            unsigned int hi = pack2bf(fmaxf(acc[mt][nt][2] + bb[2], 0.f),
                                      fmaxf(acc[mt][nt][3] + bb[3], 0.f));
            *(uint2*)(Act + swz(p, n0)) = make_uint2(lo, hi);
        }
    }
    __syncthreads();                    // Act W->R boundary

    #pragma unroll
    for (int mt = 0; mt < 4; ++mt)
        #pragma unroll
        for (int nt = 0; nt < 8; ++nt)
            acc[mt][nt] = (f32x4){0.f, 0.f, 0.f, 0.f};

    // ---- layer 2: 8 K-slices (s0 already staged into WbA) ----
    #pragma unroll
    for (int s = 0; s < 8; ++s) {
        unsigned short* cur = (s & 1) ? WbB : WbA;
        unsigned short* nxt = (s & 1) ? WbA : WbB;
        if (s < 7) stage_slice(W2e + (s+1) * SLICE_ELEMS, nxt, w, lane);
        KSLICE_BODY(cur)
        if (s < 7) __syncthreads();     // last slice needs no barrier
    }

    // ---- fused layer-2 epilogue + layer 3 (fp32, in registers) ----
    {
        f32x4 bbv[4], w3v[4];
        #pragma unroll
        for (int mt = 0; mt < 4; ++mt) {
            const int nb = w*64 + mt*16 + kg*4;
            bbv[mt] = *(const f32x4*)(b2 + e*HD + nb);
            w3v[mt] = *(const f32x4*)(W3 + e*HD + nb);
        }
        #pragma unroll
        for (int nt = 0; nt < 8; ++nt) {
            float s = 0.f;
            #pragma unroll
            for (int mt = 0; mt < 4; ++mt)
                #pragma unroll
                for (int r = 0; r < 4; ++r)
                    s += fmaxf(acc[mt][nt][r] + bbv[mt][r], 0.f) * w3v[mt][r];
            s += __shfl_xor(s, 16);   // reduce over kg (4 lanes per point)
            s += __shfl_xor(s, 32);
            if (kg == 0) pscr[(nt*16 + l15) * 4 + w] = s;
        }
    }
    __syncthreads();                    // pscr W->R boundary
    if (t < NT) {
        f32x4 v = *(const f32x4*)(pscr + t * 4);
        int p = p0 + t;
        if (p < npts) ws[e * npts + p] = v[0] + v[1] + v[2] + v[3] + b3[e];
    }
}

// Max over the 8 experts' partials.
__global__ void moe_reduce(const float* __restrict__ ws, float* __restrict__ out, int npts) {
    int p = blockIdx.x * 256 + threadIdx.x;
    if (p >= npts) return;
    float m = ws[p];
    #pragma unroll
    for (int e = 1; e < NE; ++e) m = fmaxf(m, ws[e * npts + p]);
    out[p] = m;
}

extern "C" void kernel_launch(void* const* d_in, const int* in_sizes, int n_in,
                              void* d_out, int out_size, void* d_ws, size_t ws_size,
                              hipStream_t stream) {
    const float* coords = (const float*)d_in[0];
    const float* W0 = (const float*)d_in[1];
    const float* b0 = (const float*)d_in[2];
    const float* W1 = (const float*)d_in[3];
    const float* b1 = (const float*)d_in[4];
    const float* W2 = (const float*)d_in[5];
    const float* b2 = (const float*)d_in[6];
    const float* W3 = (const float*)d_in[7];
    const float* b3 = (const float*)d_in[8];
    const int npts = in_sizes[0] / 3;

    unsigned short* W1p = (unsigned short*)d_ws;                   // 1.31 MB
    unsigned short* W2p = W1p + NE * 8 * SLICE_ELEMS;              // 1.31 MB
    float* eout = (float*)(W2p + NE * 8 * SLICE_ELEMS);            // 3.2 MB

    const int PREP_TOT = NE * 8 * SLICE_ELEMS;
    prep_weights<<<(PREP_TOT + 255) / 256, 256, 0, stream>>>(W1, W2, W1p, W2p);

    int ntiles = (npts + NT - 1) / NT;
    moe_expert<<<ntiles * NE, NTHREADS, 0, stream>>>(
        coords, npts, W0, b0, W1p, b1, W2p, b2, W3, b3, eout);

    moe_reduce<<<(npts + 255) / 256, 256, 0, stream>>>(eout, (float*)d_out, npts);
}

// Round 19
// 305.230 us; speedup vs baseline: 1.2481x; 1.2481x over previous
//
#include <hip/hip_runtime.h>
#include <hip/hip_bf16.h>

#define NE 8
#define HD 256
#define NT 128
#define NTHREADS 512
#define WPITCH 40                      // 32 k + 8 pad elems; 80 B rows (16B-aligned)
#define SLICE_ELEMS (HD * WPITCH)      // 10240 elems = 20480 B per K-slice

typedef __attribute__((ext_vector_type(8))) short short8;
typedef __attribute__((ext_vector_type(4))) float f32x4;

__device__ __forceinline__ unsigned short f2bf_u16(float f) {
    union { __hip_bfloat16 b; unsigned short u; } v;
    v.b = __float2bfloat16(f);          // HW RNE convert
    return v.u;
}
__device__ __forceinline__ unsigned int pack2bf(float lo, float hi) {
    return (unsigned int)f2bf_u16(lo) | ((unsigned int)f2bf_u16(hi) << 16);
}
// Act LDS swizzle (element units), proven in R12/R17.
__device__ __forceinline__ int swz(int row, int col) {
    return row * HD + (col ^ ((row & 7) << 3));
}

// Weights pre-swizzled: Wp[e][slice s][n][WPITCH], [n][0..31] = W[k=s*32+kk][n].
// Linear global_load_lds staging reproduces this layout in LDS verbatim.
__global__ void prep_weights(const float* __restrict__ W1, const float* __restrict__ W2,
                             unsigned short* __restrict__ W1p, unsigned short* __restrict__ W2p) {
    int idx = blockIdx.x * blockDim.x + threadIdx.x;
    const int TOT = NE * 8 * SLICE_ELEMS;
    if (idx >= TOT) return;
    int kk = idx % WPITCH;
    int n  = (idx / WPITCH) % HD;
    int s  = (idx / (WPITCH * HD)) % 8;
    int e  = idx / (WPITCH * HD * 8);
    float v1 = 0.f, v2 = 0.f;
    if (kk < 32) {
        int k = s * 32 + kk;
        v1 = W1[(e * HD + k) * HD + n];
        v2 = W2[(e * HD + k) * HD + n];
    }
    W1p[idx] = f2bf_u16(v1);
    W2p[idx] = f2bf_u16(v2);
}

// Async stage one K-slice QUARTER (neuron rows [g*64, g*64+64), 5 KB):
// issued by the h==0 wave of pair g; consumed by waves (g,0) and (g,1).
// Completion guaranteed by the per-slice __syncthreads (full vmcnt drain).
__device__ __forceinline__ void stage_slice(const unsigned short* __restrict__ gsrc,
                                            unsigned short* lbase, int g, int lane) {
    const char* gp = (const char*)gsrc + g * 5120 + lane * 16;
    char* l = (char*)lbase + g * 5120;
    #pragma unroll
    for (int i = 0; i < 5; ++i)
        __builtin_amdgcn_global_load_lds(
            (const __attribute__((address_space(1))) unsigned int*)(gp + i * 1024),
            (__attribute__((address_space(3))) unsigned int*)(l + i * 1024),
            16, 0, 0);
}

// One K-slice: 4 af (own neuron quarter) x 4 bf (own point half) -> 16 MFMA.
#define KSLICE_BODY(CURBUF)                                                                  \
    {                                                                                        \
        const unsigned short* Ar = (CURBUF) + (g*64 + l15) * WPITCH + kg*8;                  \
        short8 af0 = *(const short8*)(Ar + 0*16*WPITCH);                                     \
        short8 af1 = *(const short8*)(Ar + 1*16*WPITCH);                                     \
        short8 af2 = *(const short8*)(Ar + 2*16*WPITCH);                                     \
        short8 af3 = *(const short8*)(Ar + 3*16*WPITCH);                                     \
        const int k0 = s*32 + kg*8;                                                          \
        _Pragma("unroll")                                                                    \
        for (int nt = 0; nt < 4; ++nt) {                                                     \
            short8 bf = *(const short8*)(Act + swz(h*64 + nt*16 + l15, k0));                 \
            acc[0][nt] = __builtin_amdgcn_mfma_f32_16x16x32_bf16(af0, bf, acc[0][nt], 0,0,0);\
            acc[1][nt] = __builtin_amdgcn_mfma_f32_16x16x32_bf16(af1, bf, acc[1][nt], 0,0,0);\
            acc[2][nt] = __builtin_amdgcn_mfma_f32_16x16x32_bf16(af2, bf, acc[2][nt], 0,0,0);\
            acc[3][nt] = __builtin_amdgcn_mfma_f32_16x16x32_bf16(af3, bf, acc[3][nt], 0,0,0);\
        }                                                                                    \
    }

// One expert per block: blockIdx = tile*8 + e (expert<->XCD affinity).
// 8 waves: wave (g = w>>1, h = w&1) owns neurons [g*64,+64) x points [h*64,+64).
// m97-style schedule: stage(next) -> compute(cur) -> __syncthreads per slice.
__global__ __launch_bounds__(NTHREADS, 2) void moe_expert(
    const float* __restrict__ coords, int npts,
    const float* __restrict__ W0, const float* __restrict__ b0,
    const unsigned short* __restrict__ W1p, const float* __restrict__ b1,
    const unsigned short* __restrict__ W2p, const float* __restrict__ b2,
    const float* __restrict__ W3, const float* __restrict__ b3,
    float* __restrict__ ws)
{
    __shared__ __align__(16) unsigned short Act[NT * HD];      // 64 KB
    __shared__ __align__(16) unsigned short WbA[SLICE_ELEMS];  // 20 KB
    __shared__ __align__(16) unsigned short WbB[SLICE_ELEMS];  // 20 KB
    __shared__ float cbuf[NT * 3];                             // 1.5 KB
    __shared__ float pscr[NT * 4];                             // 2 KB

    const int t = threadIdx.x;
    const int lane = t & 63;
    const int w = t >> 6;       // 0..7
    const int g = w >> 1;       // 0..3: neuron group of 64
    const int h = w & 1;        // 0..1: point half of 64
    const int l15 = lane & 15;
    const int kg = lane >> 4;
    const int e = blockIdx.x & 7;
    const int p0 = (blockIdx.x >> 3) * NT;

    const unsigned short* W1e = W1p + e * 8 * SLICE_ELEMS;
    const unsigned short* W2e = W2p + e * 8 * SLICE_ELEMS;

    if (t < NT * 3) {
        int idx = p0 * 3 + t;
        int lim = npts * 3 - 1;
        cbuf[t] = coords[idx < lim ? idx : lim];   // clamp; store masked later
    }
    const int j2 = (t & 127) * 2;            // 2 consecutive neurons
    const int prow0 = (t >> 7) * 32;         // 32 points per quarter
    const float wx0 = W0[(e*3+0)*HD + j2], wx1 = W0[(e*3+0)*HD + j2+1];
    const float wy0 = W0[(e*3+1)*HD + j2], wy1 = W0[(e*3+1)*HD + j2+1];
    const float wz0 = W0[(e*3+2)*HD + j2], wz1 = W0[(e*3+2)*HD + j2+1];
    const float bb0 = b0[e*HD + j2],       bb1 = b0[e*HD + j2+1];
    f32x4 b1v[4];
    #pragma unroll
    for (int mt = 0; mt < 4; ++mt)
        b1v[mt] = *(const f32x4*)(b1 + e*HD + g*64 + mt*16 + kg*4);
    __syncthreads();                    // cbuf visible

    // ---- kick off layer-1 slice 0 staging; hidden under L0 compute ----
    if (h == 0) stage_slice(W1e, WbA, g, lane);

    // ---- layer 0: 3 -> 256, fp32 VALU, packed writes into Act ----
    #pragma unroll 4
    for (int pp = 0; pp < 32; ++pp) {
        int p = prow0 + pp;
        float x = cbuf[p*3], y = cbuf[p*3+1], z = cbuf[p*3+2];
        float h0 = fmaxf(x*wx0 + y*wy0 + z*wz0 + bb0, 0.f);
        float h1 = fmaxf(x*wx1 + y*wy1 + z*wz1 + bb1, 0.f);
        *(unsigned int*)(Act + swz(p, j2)) = pack2bf(h0, h1);
    }
    __syncthreads();                    // Act ready + slice-0 staging drained

    f32x4 acc[4][4];
    #pragma unroll
    for (int mt = 0; mt < 4; ++mt)
        #pragma unroll
        for (int nt = 0; nt < 4; ++nt)
            acc[mt][nt] = (f32x4){0.f, 0.f, 0.f, 0.f};

    // ---- layer 1: 8 K-slices, double-buffered; one __syncthreads per slice ----
    #pragma unroll
    for (int s = 0; s < 8; ++s) {
        unsigned short* cur = (s & 1) ? WbB : WbA;
        unsigned short* nxt = (s & 1) ? WbA : WbB;
        if (h == 0) {
            if (s < 7) stage_slice(W1e + (s+1) * SLICE_ELEMS, nxt, g, lane);
            else       stage_slice(W2e, nxt, g, lane);      // chain layer-2 s0
        }
        KSLICE_BODY(cur)
        __syncthreads();                // drains DMA (nxt ready) + fence
    }

    // ---- layer-1 epilogue: bias+relu -> Act in place ----
    #pragma unroll
    for (int mt = 0; mt < 4; ++mt) {
        const int n0 = g*64 + mt*16 + kg*4;
        const f32x4 bb = b1v[mt];
        #pragma unroll
        for (int nt = 0; nt < 4; ++nt) {
            const int p = h*64 + nt*16 + l15;
            unsigned int lo = pack2bf(fmaxf(acc[mt][nt][0] + bb[0], 0.f),
                                      fmaxf(acc[mt][nt][1] + bb[1], 0.f));
            unsigned int hi = pack2bf(fmaxf(acc[mt][nt][2] + bb[2], 0.f),
                                      fmaxf(acc[mt][nt][3] + bb[3], 0.f));
            *(uint2*)(Act + swz(p, n0)) = make_uint2(lo, hi);
        }
    }
    __syncthreads();                    // Act W->R boundary

    #pragma unroll
    for (int mt = 0; mt < 4; ++mt)
        #pragma unroll
        for (int nt = 0; nt < 4; ++nt)
            acc[mt][nt] = (f32x4){0.f, 0.f, 0.f, 0.f};

    // ---- layer 2: 8 K-slices (s0 already staged into WbA) ----
    #pragma unroll
    for (int s = 0; s < 8; ++s) {
        unsigned short* cur = (s & 1) ? WbB : WbA;
        unsigned short* nxt = (s & 1) ? WbA : WbB;
        if (h == 0 && s < 7) stage_slice(W2e + (s+1) * SLICE_ELEMS, nxt, g, lane);
        KSLICE_BODY(cur)
        if (s < 7) __syncthreads();     // last slice needs no barrier
    }

    // ---- fused layer-2 epilogue + layer 3 (fp32, in registers) ----
    {
        f32x4 bbv[4], w3v[4];
        #pragma unroll
        for (int mt = 0; mt < 4; ++mt) {
            const int nb = g*64 + mt*16 + kg*4;
            bbv[mt] = *(const f32x4*)(b2 + e*HD + nb);
            w3v[mt] = *(const f32x4*)(W3 + e*HD + nb);
        }
        #pragma unroll
        for (int nt = 0; nt < 4; ++nt) {
            float s = 0.f;
            #pragma unroll
            for (int mt = 0; mt < 4; ++mt)
                #pragma unroll
                for (int r = 0; r < 4; ++r)
                    s += fmaxf(acc[mt][nt][r] + bbv[mt][r], 0.f) * w3v[mt][r];
            s += __shfl_xor(s, 16);   // reduce over kg (4 lanes per point)
            s += __shfl_xor(s, 32);
            if (kg == 0) pscr[(h*64 + nt*16 + l15) * 4 + g] = s;
        }
    }
    __syncthreads();                    // pscr W->R boundary
    if (t < NT) {
        f32x4 v = *(const f32x4*)(pscr + t * 4);
        int p = p0 + t;
        if (p < npts) ws[e * npts + p] = v[0] + v[1] + v[2] + v[3] + b3[e];
    }
}

// Max over the 8 experts' partials.
__global__ void moe_reduce(const float* __restrict__ ws, float* __restrict__ out, int npts) {
    int p = blockIdx.x * 256 + threadIdx.x;
    if (p >= npts) return;
    float m = ws[p];
    #pragma unroll
    for (int e = 1; e < NE; ++e) m = fmaxf(m, ws[e * npts + p]);
    out[p] = m;
}

extern "C" void kernel_launch(void* const* d_in, const int* in_sizes, int n_in,
                              void* d_out, int out_size, void* d_ws, size_t ws_size,
                              hipStream_t stream) {
    const float* coords = (const float*)d_in[0];
    const float* W0 = (const float*)d_in[1];
    const float* b0 = (const float*)d_in[2];
    const float* W1 = (const float*)d_in[3];
    const float* b1 = (const float*)d_in[4];
    const float* W2 = (const float*)d_in[5];
    const float* b2 = (const float*)d_in[6];
    const float* W3 = (const float*)d_in[7];
    const float* b3 = (const float*)d_in[8];
    const int npts = in_sizes[0] / 3;

    unsigned short* W1p = (unsigned short*)d_ws;                   // 1.31 MB
    unsigned short* W2p = W1p + NE * 8 * SLICE_ELEMS;              // 1.31 MB
    float* eout = (float*)(W2p + NE * 8 * SLICE_ELEMS);            // 3.2 MB

    const int PREP_TOT = NE * 8 * SLICE_ELEMS;
    prep_weights<<<(PREP_TOT + 255) / 256, 256, 0, stream>>>(W1, W2, W1p, W2p);

    int ntiles = (npts + NT - 1) / NT;
    moe_expert<<<ntiles * NE, NTHREADS, 0, stream>>>(
        coords, npts, W0, b0, W1p, b1, W2p, b2, W3, b3, eout);

    moe_reduce<<<(npts + 255) / 256, 256, 0, stream>>>(eout, (float*)d_out, npts);
}

// Round 20
// 279.913 us; speedup vs baseline: 1.3610x; 1.0904x over previous
//
#include <hip/hip_runtime.h>
#include <hip/hip_bf16.h>

#define NE 8
#define HD 256
#define NT 64
#define NTHREADS 512
#define WPITCH 32                      // no pad: af start-banks already uniform
#define SLICE_ELEMS (HD * WPITCH)      // 8192 elems = 16384 B per K-slice

typedef __attribute__((ext_vector_type(8))) short short8;
typedef __attribute__((ext_vector_type(4))) float f32x4;

__device__ __forceinline__ unsigned short f2bf_u16(float f) {
    union { __hip_bfloat16 b; unsigned short u; } v;
    v.b = __float2bfloat16(f);          // HW RNE convert
    return v.u;
}
__device__ __forceinline__ unsigned int pack2bf(float lo, float hi) {
    return (unsigned int)f2bf_u16(lo) | ((unsigned int)f2bf_u16(hi) << 16);
}
// Act LDS swizzle (element units), proven in R12/R17.
__device__ __forceinline__ int swz(int row, int col) {
    return row * HD + (col ^ ((row & 7) << 3));
}

// Weights pre-swizzled: Wp[e][slice s][n][32], [n][kk] = W[k=s*32+kk][n].
// Linear global_load_lds staging reproduces this layout in LDS verbatim.
__global__ void prep_weights(const float* __restrict__ W1, const float* __restrict__ W2,
                             unsigned short* __restrict__ W1p, unsigned short* __restrict__ W2p) {
    int idx = blockIdx.x * blockDim.x + threadIdx.x;
    const int TOT = NE * 8 * SLICE_ELEMS;
    if (idx >= TOT) return;
    int kk = idx & 31;
    int n  = (idx >> 5) & 255;
    int s  = (idx >> 13) & 7;
    int e  = idx >> 16;
    int k = s * 32 + kk;
    W1p[idx] = f2bf_u16(W1[(e * HD + k) * HD + n]);
    W2p[idx] = f2bf_u16(W2[(e * HD + k) * HD + n]);
}

// Async stage one K-slice QUARTER (neuron rows [g*64, g*64+64), 4 KB):
// issued by the h==0 wave of pair g; consumed by waves (g,0) and (g,1).
// Completion guaranteed by the per-slice __syncthreads (full vmcnt drain).
__device__ __forceinline__ void stage_slice(const unsigned short* __restrict__ gsrc,
                                            unsigned short* lbase, int g, int lane) {
    const char* gp = (const char*)gsrc + g * 4096 + lane * 16;
    char* l = (char*)lbase + g * 4096;
    #pragma unroll
    for (int i = 0; i < 4; ++i)
        __builtin_amdgcn_global_load_lds(
            (const __attribute__((address_space(1))) unsigned int*)(gp + i * 1024),
            (__attribute__((address_space(3))) unsigned int*)(l + i * 1024),
            16, 0, 0);
}

// One K-slice: 4 af (own neuron quarter) x 2 bf (own 32-pt half) -> 8 MFMA.
#define KSLICE_BODY(CURBUF)                                                                  \
    {                                                                                        \
        const unsigned short* Ar = (CURBUF) + (g*64 + l15) * WPITCH + kg*8;                  \
        short8 af0 = *(const short8*)(Ar + 0*16*WPITCH);                                     \
        short8 af1 = *(const short8*)(Ar + 1*16*WPITCH);                                     \
        short8 af2 = *(const short8*)(Ar + 2*16*WPITCH);                                     \
        short8 af3 = *(const short8*)(Ar + 3*16*WPITCH);                                     \
        const int k0 = s*32 + kg*8;                                                          \
        _Pragma("unroll")                                                                    \
        for (int nt = 0; nt < 2; ++nt) {                                                     \
            short8 bf = *(const short8*)(Act + swz(h*32 + nt*16 + l15, k0));                 \
            acc[0][nt] = __builtin_amdgcn_mfma_f32_16x16x32_bf16(af0, bf, acc[0][nt], 0,0,0);\
            acc[1][nt] = __builtin_amdgcn_mfma_f32_16x16x32_bf16(af1, bf, acc[1][nt], 0,0,0);\
            acc[2][nt] = __builtin_amdgcn_mfma_f32_16x16x32_bf16(af2, bf, acc[2][nt], 0,0,0);\
            acc[3][nt] = __builtin_amdgcn_mfma_f32_16x16x32_bf16(af3, bf, acc[3][nt], 0,0,0);\
        }                                                                                    \
    }

// One expert per block: blockIdx = tile*8 + e (expert<->XCD affinity).
// 8 waves: wave (g = w>>1, h = w&1) owns neurons [g*64,+64) x points [h*32,+32).
// LDS ~67 KB -> 2 blocks/CU -> 4 waves/SIMD (the latency-hiding this round adds).
__global__ __launch_bounds__(NTHREADS, 2) void moe_expert(
    const float* __restrict__ coords, int npts,
    const float* __restrict__ W0, const float* __restrict__ b0,
    const unsigned short* __restrict__ W1p, const float* __restrict__ b1,
    const unsigned short* __restrict__ W2p, const float* __restrict__ b2,
    const float* __restrict__ W3, const float* __restrict__ b3,
    float* __restrict__ ws)
{
    __shared__ __align__(16) unsigned short Act[NT * HD];      // 32 KB
    __shared__ __align__(16) unsigned short WbA[SLICE_ELEMS];  // 16 KB
    __shared__ __align__(16) unsigned short WbB[SLICE_ELEMS];  // 16 KB
    __shared__ float cbuf[NT * 3];                             // 768 B
    __shared__ float pscr[NT * 4];                             // 1 KB

    const int t = threadIdx.x;
    const int lane = t & 63;
    const int w = t >> 6;       // 0..7
    const int g = w >> 1;       // 0..3: neuron group of 64
    const int h = w & 1;        // 0..1: point half of 32
    const int l15 = lane & 15;
    const int kg = lane >> 4;
    const int e = blockIdx.x & 7;
    const int p0 = (blockIdx.x >> 3) * NT;

    const unsigned short* W1e = W1p + e * 8 * SLICE_ELEMS;
    const unsigned short* W2e = W2p + e * 8 * SLICE_ELEMS;

    if (t < NT * 3) {
        int idx = p0 * 3 + t;
        int lim = npts * 3 - 1;
        cbuf[t] = coords[idx < lim ? idx : lim];   // clamp; store masked later
    }
    const int j2 = (t & 127) * 2;            // 2 consecutive neurons
    const int prow0 = (t >> 7) * 16;         // 16 points per quarter
    const float wx0 = W0[(e*3+0)*HD + j2], wx1 = W0[(e*3+0)*HD + j2+1];
    const float wy0 = W0[(e*3+1)*HD + j2], wy1 = W0[(e*3+1)*HD + j2+1];
    const float wz0 = W0[(e*3+2)*HD + j2], wz1 = W0[(e*3+2)*HD + j2+1];
    const float bb0 = b0[e*HD + j2],       bb1 = b0[e*HD + j2+1];
    f32x4 b1v[4];
    #pragma unroll
    for (int mt = 0; mt < 4; ++mt)
        b1v[mt] = *(const f32x4*)(b1 + e*HD + g*64 + mt*16 + kg*4);
    __syncthreads();                    // cbuf visible

    // ---- kick off layer-1 slice 0 staging; hidden under L0 compute ----
    if (h == 0) stage_slice(W1e, WbA, g, lane);

    // ---- layer 0: 3 -> 256, fp32 VALU, packed writes into Act ----
    #pragma unroll 4
    for (int pp = 0; pp < 16; ++pp) {
        int p = prow0 + pp;
        float x = cbuf[p*3], y = cbuf[p*3+1], z = cbuf[p*3+2];
        float h0 = fmaxf(x*wx0 + y*wy0 + z*wz0 + bb0, 0.f);
        float h1 = fmaxf(x*wx1 + y*wy1 + z*wz1 + bb1, 0.f);
        *(unsigned int*)(Act + swz(p, j2)) = pack2bf(h0, h1);
    }
    __syncthreads();                    // Act ready + slice-0 staging drained

    f32x4 acc[4][2];
    #pragma unroll
    for (int mt = 0; mt < 4; ++mt)
        #pragma unroll
        for (int nt = 0; nt < 2; ++nt)
            acc[mt][nt] = (f32x4){0.f, 0.f, 0.f, 0.f};

    // ---- layer 1: 8 K-slices, double-buffered; one __syncthreads per slice ----
    #pragma unroll
    for (int s = 0; s < 8; ++s) {
        unsigned short* cur = (s & 1) ? WbB : WbA;
        unsigned short* nxt = (s & 1) ? WbA : WbB;
        if (h == 0) {
            if (s < 7) stage_slice(W1e + (s+1) * SLICE_ELEMS, nxt, g, lane);
            else       stage_slice(W2e, nxt, g, lane);      // chain layer-2 s0
        }
        KSLICE_BODY(cur)
        __syncthreads();                // drains DMA (nxt ready) + fence
    }

    // ---- layer-1 epilogue: bias+relu -> Act in place ----
    #pragma unroll
    for (int mt = 0; mt < 4; ++mt) {
        const int n0 = g*64 + mt*16 + kg*4;
        const f32x4 bb = b1v[mt];
        #pragma unroll
        for (int nt = 0; nt < 2; ++nt) {
            const int p = h*32 + nt*16 + l15;
            unsigned int lo = pack2bf(fmaxf(acc[mt][nt][0] + bb[0], 0.f),
                                      fmaxf(acc[mt][nt][1] + bb[1], 0.f));
            unsigned int hi = pack2bf(fmaxf(acc[mt][nt][2] + bb[2], 0.f),
                                      fmaxf(acc[mt][nt][3] + bb[3], 0.f));
            *(uint2*)(Act + swz(p, n0)) = make_uint2(lo, hi);
        }
    }
    __syncthreads();                    // Act W->R boundary

    #pragma unroll
    for (int mt = 0; mt < 4; ++mt)
        #pragma unroll
        for (int nt = 0; nt < 2; ++nt)
            acc[mt][nt] = (f32x4){0.f, 0.f, 0.f, 0.f};

    // ---- layer 2: 8 K-slices (s0 already staged into WbA) ----
    #pragma unroll
    for (int s = 0; s < 8; ++s) {
        unsigned short* cur = (s & 1) ? WbB : WbA;
        unsigned short* nxt = (s & 1) ? WbA : WbB;
        if (h == 0 && s < 7) stage_slice(W2e + (s+1) * SLICE_ELEMS, nxt, g, lane);
        KSLICE_BODY(cur)
        if (s < 7) __syncthreads();     // last slice needs no barrier
    }

    // ---- fused layer-2 epilogue + layer 3 (fp32, in registers) ----
    {
        f32x4 bbv[4], w3v[4];
        #pragma unroll
        for (int mt = 0; mt < 4; ++mt) {
            const int nb = g*64 + mt*16 + kg*4;
            bbv[mt] = *(const f32x4*)(b2 + e*HD + nb);
            w3v[mt] = *(const f32x4*)(W3 + e*HD + nb);
        }
        #pragma unroll
        for (int nt = 0; nt < 2; ++nt) {
            float s = 0.f;
            #pragma unroll
            for (int mt = 0; mt < 4; ++mt)
                #pragma unroll
                for (int r = 0; r < 4; ++r)
                    s += fmaxf(acc[mt][nt][r] + bbv[mt][r], 0.f) * w3v[mt][r];
            s += __shfl_xor(s, 16);   // reduce over kg (4 lanes per point)
            s += __shfl_xor(s, 32);
            if (kg == 0) pscr[(h*32 + nt*16 + l15) * 4 + g] = s;
        }
    }
    __syncthreads();                    // pscr W->R boundary
    if (t < NT) {
        f32x4 v = *(const f32x4*)(pscr + t * 4);
        int p = p0 + t;
        if (p < npts) ws[e * npts + p] = v[0] + v[1] + v[2] + v[3] + b3[e];
    }
}

// Max over the 8 experts' partials.
__global__ void moe_reduce(const float* __restrict__ ws, float* __restrict__ out, int npts) {
    int p = blockIdx.x * 256 + threadIdx.x;
    if (p >= npts) return;
    float m = ws[p];
    #pragma unroll
    for (int e = 1; e < NE; ++e) m = fmaxf(m, ws[e * npts + p]);
    out[p] = m;
}

extern "C" void kernel_launch(void* const* d_in, const int* in_sizes, int n_in,
                              void* d_out, int out_size, void* d_ws, size_t ws_size,
                              hipStream_t stream) {
    const float* coords = (const float*)d_in[0];
    const float* W0 = (const float*)d_in[1];
    const float* b0 = (const float*)d_in[2];
    const float* W1 = (const float*)d_in[3];
    const float* b1 = (const float*)d_in[4];
    const float* W2 = (const float*)d_in[5];
    const float* b2 = (const float*)d_in[6];
    const float* W3 = (const float*)d_in[7];
    const float* b3 = (const float*)d_in[8];
    const int npts = in_sizes[0] / 3;

    unsigned short* W1p = (unsigned short*)d_ws;                   // 1 MB
    unsigned short* W2p = W1p + NE * 8 * SLICE_ELEMS;              // 1 MB
    float* eout = (float*)(W2p + NE * 8 * SLICE_ELEMS);            // 3.2 MB

    const int PREP_TOT = NE * 8 * SLICE_ELEMS;
    prep_weights<<<(PREP_TOT + 255) / 256, 256, 0, stream>>>(W1, W2, W1p, W2p);

    int ntiles = (npts + NT - 1) / NT;
    moe_expert<<<ntiles * NE, NTHREADS, 0, stream>>>(
        coords, npts, W0, b0, W1p, b1, W2p, b2, W3, b3, eout);

    moe_reduce<<<(npts + 255) / 256, 256, 0, stream>>>(eout, (float*)d_out, npts);
}

// Round 21
// 272.698 us; speedup vs baseline: 1.3970x; 1.0265x over previous
//
#include <hip/hip_runtime.h>
#include <hip/hip_bf16.h>

#define NE 8
#define HD 256
#define NT 64
#define NTHREADS 512
#define WPITCH 32                      // af start-banks uniform; no pad needed
#define SLICE_ELEMS (HD * WPITCH)      // 8192 elems = 16384 B per K-slice

typedef __attribute__((ext_vector_type(8))) short short8;
typedef __attribute__((ext_vector_type(4))) float f32x4;

__device__ __forceinline__ unsigned short f2bf_u16(float f) {
    union { __hip_bfloat16 b; unsigned short u; } v;
    v.b = __float2bfloat16(f);          // HW RNE convert
    return v.u;
}
__device__ __forceinline__ unsigned int pack2bf(float lo, float hi) {
    return (unsigned int)f2bf_u16(lo) | ((unsigned int)f2bf_u16(hi) << 16);
}
// hi/lo bf16 split: v ≈ hi + lo with |v - hi - lo| <= 2^-16 |v|.
__device__ __forceinline__ void bfsplit(float v, unsigned short& hi, unsigned short& lo) {
    hi = f2bf_u16(v);
    union { unsigned int u; float f; } c; c.u = ((unsigned int)hi) << 16;
    lo = f2bf_u16(v - c.f);
}
// Act LDS swizzle (element units), proven in R12/R17.
__device__ __forceinline__ int swz(int row, int col) {
    return row * HD + (col ^ ((row & 7) << 3));
}

// Weights pre-swizzled: Wp[e][slice s][n][32], [n][kk] = W[k=s*32+kk][n].
__global__ void prep_weights(const float* __restrict__ W1, const float* __restrict__ W2,
                             unsigned short* __restrict__ W1p, unsigned short* __restrict__ W2p) {
    int idx = blockIdx.x * blockDim.x + threadIdx.x;
    const int TOT = NE * 8 * SLICE_ELEMS;
    if (idx >= TOT) return;
    int kk = idx & 31;
    int n  = (idx >> 5) & 255;
    int s  = (idx >> 13) & 7;
    int e  = idx >> 16;
    int k = s * 32 + kk;
    W1p[idx] = f2bf_u16(W1[(e * HD + k) * HD + n]);
    W2p[idx] = f2bf_u16(W2[(e * HD + k) * HD + n]);
}

// Layer-0 as a K=32 MFMA slice: A-slots per neuron n:
//  0:wx_hi 1:wx_hi 2:wx_lo | 3:wy_hi 4:wy_hi 5:wy_lo | 6:wz_hi 7:wz_hi 8:wz_lo
//  9:b0_hi 10:b0_lo | 11..31: 0    (pairs with B-slots built in cbufK)
__global__ void prep_w0(const float* __restrict__ W0, const float* __restrict__ b0,
                        unsigned short* __restrict__ W0k) {
    int idx = blockIdx.x * blockDim.x + threadIdx.x;   // e*HD + n
    if (idx >= NE * HD) return;
    int n = idx & 255, e = idx >> 8;
    float wx = W0[(e*3+0)*HD + n], wy = W0[(e*3+1)*HD + n], wz = W0[(e*3+2)*HD + n];
    float bb = b0[e*HD + n];
    unsigned short xh,xl,yh,yl,zh,zl,bh,bl;
    bfsplit(wx,xh,xl); bfsplit(wy,yh,yl); bfsplit(wz,zh,zl); bfsplit(bb,bh,bl);
    unsigned short s[32] = {xh,xh,xl, yh,yh,yl, zh,zh,zl, bh,bl};  // rest zero
    unsigned short* dst = W0k + idx * 32;
    #pragma unroll
    for (int i = 0; i < 32; ++i) dst[i] = s[i];
}

// Async stage one K-slice QUARTER (neuron rows [g*64, g*64+64), 4 KB):
// issued by the h==0 wave of pair g. Completion via __syncthreads (vmcnt drain).
__device__ __forceinline__ void stage_slice(const unsigned short* __restrict__ gsrc,
                                            unsigned short* lbase, int g, int lane) {
    const char* gp = (const char*)gsrc + g * 4096 + lane * 16;
    char* l = (char*)lbase + g * 4096;
    #pragma unroll
    for (int i = 0; i < 4; ++i)
        __builtin_amdgcn_global_load_lds(
            (const __attribute__((address_space(1))) unsigned int*)(gp + i * 1024),
            (__attribute__((address_space(3))) unsigned int*)(l + i * 1024),
            16, 0, 0);
}

// One K-slice: 4 af (own neuron quarter) x 2 bf (own 32-pt half) -> 8 MFMA.
#define KSLICE_BODY(CURBUF)                                                                  \
    {                                                                                        \
        const unsigned short* Ar = (CURBUF) + (g*64 + l15) * WPITCH + kg*8;                  \
        short8 af0 = *(const short8*)(Ar + 0*16*WPITCH);                                     \
        short8 af1 = *(const short8*)(Ar + 1*16*WPITCH);                                     \
        short8 af2 = *(const short8*)(Ar + 2*16*WPITCH);                                     \
        short8 af3 = *(const short8*)(Ar + 3*16*WPITCH);                                     \
        const int k0 = s*32 + kg*8;                                                          \
        _Pragma("unroll")                                                                    \
        for (int nt = 0; nt < 2; ++nt) {                                                     \
            short8 bf = *(const short8*)(Act + swz(h*32 + nt*16 + l15, k0));                 \
            acc[0][nt] = __builtin_amdgcn_mfma_f32_16x16x32_bf16(af0, bf, acc[0][nt], 0,0,0);\
            acc[1][nt] = __builtin_amdgcn_mfma_f32_16x16x32_bf16(af1, bf, acc[1][nt], 0,0,0);\
            acc[2][nt] = __builtin_amdgcn_mfma_f32_16x16x32_bf16(af2, bf, acc[2][nt], 0,0,0);\
            acc[3][nt] = __builtin_amdgcn_mfma_f32_16x16x32_bf16(af3, bf, acc[3][nt], 0,0,0);\
        }                                                                                    \
    }

// One expert per block: blockIdx = tile*8 + e. 8 waves: wave (g=w>>1, h=w&1)
// owns neurons [g*64,+64) x points [h*32,+32). ~71 KB LDS -> 2 blocks/CU.
__global__ __launch_bounds__(NTHREADS, 2) void moe_expert(
    const float* __restrict__ coords, int npts,
    const unsigned short* __restrict__ W0k, const float* __restrict__ b1,
    const unsigned short* __restrict__ W1p,
    const unsigned short* __restrict__ W2p, const float* __restrict__ b2,
    const float* __restrict__ W3, const float* __restrict__ b3,
    float* __restrict__ ws)
{
    __shared__ __align__(16) unsigned short Act[NT * HD];      // 32 KB
    __shared__ __align__(16) unsigned short WbA[SLICE_ELEMS];  // 16 KB
    __shared__ __align__(16) unsigned short WbB[SLICE_ELEMS];  // 16 KB
    __shared__ __align__(16) unsigned short cbufK[NT * 32];    // 4 KB: L0 B-slots
    __shared__ float pscr[NT * 4];                             // 1 KB

    const int t = threadIdx.x;
    const int lane = t & 63;
    const int w = t >> 6;       // 0..7
    const int g = w >> 1;       // 0..3: neuron group of 64
    const int h = w & 1;        // 0..1: point half of 32
    const int l15 = lane & 15;
    const int kg = lane >> 4;
    const int e = blockIdx.x & 7;
    const int p0 = (blockIdx.x >> 3) * NT;

    const unsigned short* W0e = W0k + e * SLICE_ELEMS;
    const unsigned short* W1e = W1p + e * 8 * SLICE_ELEMS;
    const unsigned short* W2e = W2p + e * 8 * SLICE_ELEMS;

    // ---- phase 0: stage W0k slice; build per-point B-slots (hi/lo split) ----
    if (h == 0) stage_slice(W0e, WbB, g, lane);
    if (t < NT) {
        int p = p0 + t;
        int pc = p < npts ? p : npts - 1;      // clamp; store masked later
        float x = coords[pc*3], y = coords[pc*3+1], z = coords[pc*3+2];
        unsigned short xh,xl,yh,yl,zh,zl;
        bfsplit(x,xh,xl); bfsplit(y,yh,yl); bfsplit(z,zh,zl);
        const unsigned short ONE = 0x3F80;     // bf16(1.0)
        union { unsigned short s[32]; uint4 q[4]; } pk;
        #pragma unroll
        for (int i = 0; i < 32; ++i) pk.s[i] = 0;
        pk.s[0]=xh; pk.s[1]=xl; pk.s[2]=xh;
        pk.s[3]=yh; pk.s[4]=yl; pk.s[5]=yh;
        pk.s[6]=zh; pk.s[7]=zl; pk.s[8]=zh;
        pk.s[9]=ONE; pk.s[10]=ONE;
        uint4* dst = (uint4*)(cbufK + t * 32);
        dst[0]=pk.q[0]; dst[1]=pk.q[1]; dst[2]=pk.q[2]; dst[3]=pk.q[3];
    }
    f32x4 b1v[4];
    #pragma unroll
    for (int mt = 0; mt < 4; ++mt)
        b1v[mt] = *(const f32x4*)(b1 + e*HD + g*64 + mt*16 + kg*4);
    __syncthreads();                    // cbufK visible + W0k staged (vmcnt drained)

    f32x4 acc[4][2];
    #pragma unroll
    for (int mt = 0; mt < 4; ++mt)
        #pragma unroll
        for (int nt = 0; nt < 2; ++nt)
            acc[mt][nt] = (f32x4){0.f, 0.f, 0.f, 0.f};

    // ---- phase 1: L0 as one MFMA K-slice (bias in slots); stage L1 s0 ----
    if (h == 0) stage_slice(W1e, WbA, g, lane);
    {
        const unsigned short* Ar = WbB + (g*64 + l15) * WPITCH + kg*8;
        short8 af0 = *(const short8*)(Ar + 0*16*WPITCH);
        short8 af1 = *(const short8*)(Ar + 1*16*WPITCH);
        short8 af2 = *(const short8*)(Ar + 2*16*WPITCH);
        short8 af3 = *(const short8*)(Ar + 3*16*WPITCH);
        #pragma unroll
        for (int nt = 0; nt < 2; ++nt) {
            short8 bf = *(const short8*)(cbufK + (h*32 + nt*16 + l15) * 32 + kg*8);
            acc[0][nt] = __builtin_amdgcn_mfma_f32_16x16x32_bf16(af0, bf, acc[0][nt], 0,0,0);
            acc[1][nt] = __builtin_amdgcn_mfma_f32_16x16x32_bf16(af1, bf, acc[1][nt], 0,0,0);
            acc[2][nt] = __builtin_amdgcn_mfma_f32_16x16x32_bf16(af2, bf, acc[2][nt], 0,0,0);
            acc[3][nt] = __builtin_amdgcn_mfma_f32_16x16x32_bf16(af3, bf, acc[3][nt], 0,0,0);
        }
        // L0 epilogue: relu + pack -> Act (bias already in the MFMA slots)
        #pragma unroll
        for (int mt = 0; mt < 4; ++mt)
            #pragma unroll
            for (int nt = 0; nt < 2; ++nt) {
                const int p = h*32 + nt*16 + l15;
                const int n0 = g*64 + mt*16 + kg*4;
                unsigned int lo = pack2bf(fmaxf(acc[mt][nt][0], 0.f),
                                          fmaxf(acc[mt][nt][1], 0.f));
                unsigned int hi = pack2bf(fmaxf(acc[mt][nt][2], 0.f),
                                          fmaxf(acc[mt][nt][3], 0.f));
                *(uint2*)(Act + swz(p, n0)) = make_uint2(lo, hi);
            }
    }
    __syncthreads();                    // Act ready + L1 s0 staged

    #pragma unroll
    for (int mt = 0; mt < 4; ++mt)
        #pragma unroll
        for (int nt = 0; nt < 2; ++nt)
            acc[mt][nt] = (f32x4){0.f, 0.f, 0.f, 0.f};

    // ---- layer 1: 8 K-slices, double-buffered; one __syncthreads per slice ----
    #pragma unroll
    for (int s = 0; s < 8; ++s) {
        unsigned short* cur = (s & 1) ? WbB : WbA;
        unsigned short* nxt = (s & 1) ? WbA : WbB;
        if (h == 0) {
            if (s < 7) stage_slice(W1e + (s+1) * SLICE_ELEMS, nxt, g, lane);
            else       stage_slice(W2e, nxt, g, lane);      // chain layer-2 s0
        }
        KSLICE_BODY(cur)
        __syncthreads();                // drains DMA (nxt ready) + fence
    }

    // ---- layer-1 epilogue: bias+relu -> Act in place ----
    #pragma unroll
    for (int mt = 0; mt < 4; ++mt) {
        const int n0 = g*64 + mt*16 + kg*4;
        const f32x4 bb = b1v[mt];
        #pragma unroll
        for (int nt = 0; nt < 2; ++nt) {
            const int p = h*32 + nt*16 + l15;
            unsigned int lo = pack2bf(fmaxf(acc[mt][nt][0] + bb[0], 0.f),
                                      fmaxf(acc[mt][nt][1] + bb[1], 0.f));
            unsigned int hi = pack2bf(fmaxf(acc[mt][nt][2] + bb[2], 0.f),
                                      fmaxf(acc[mt][nt][3] + bb[3], 0.f));
            *(uint2*)(Act + swz(p, n0)) = make_uint2(lo, hi);
        }
    }
    __syncthreads();                    // Act W->R boundary

    #pragma unroll
    for (int mt = 0; mt < 4; ++mt)
        #pragma unroll
        for (int nt = 0; nt < 2; ++nt)
            acc[mt][nt] = (f32x4){0.f, 0.f, 0.f, 0.f};

    // ---- layer 2: 8 K-slices (s0 already staged into WbA) ----
    #pragma unroll
    for (int s = 0; s < 8; ++s) {
        unsigned short* cur = (s & 1) ? WbB : WbA;
        unsigned short* nxt = (s & 1) ? WbA : WbB;
        if (h == 0 && s < 7) stage_slice(W2e + (s+1) * SLICE_ELEMS, nxt, g, lane);
        KSLICE_BODY(cur)
        if (s < 7) __syncthreads();     // last slice needs no barrier
    }

    // ---- fused layer-2 epilogue + layer 3 (fp32, in registers) ----
    {
        f32x4 bbv[4], w3v[4];
        #pragma unroll
        for (int mt = 0; mt < 4; ++mt) {
            const int nb = g*64 + mt*16 + kg*4;
            bbv[mt] = *(const f32x4*)(b2 + e*HD + nb);
            w3v[mt] = *(const f32x4*)(W3 + e*HD + nb);
        }
        #pragma unroll
        for (int nt = 0; nt < 2; ++nt) {
            float s = 0.f;
            #pragma unroll
            for (int mt = 0; mt < 4; ++mt)
                #pragma unroll
                for (int r = 0; r < 4; ++r)
                    s += fmaxf(acc[mt][nt][r] + bbv[mt][r], 0.f) * w3v[mt][r];
            s += __shfl_xor(s, 16);   // reduce over kg (4 lanes per point)
            s += __shfl_xor(s, 32);
            if (kg == 0) pscr[(h*32 + nt*16 + l15) * 4 + g] = s;
        }
    }
    __syncthreads();                    // pscr W->R boundary
    if (t < NT) {
        f32x4 v = *(const f32x4*)(pscr + t * 4);
        int p = p0 + t;
        if (p < npts) ws[e * npts + p] = v[0] + v[1] + v[2] + v[3] + b3[e];
    }
}

// Max over the 8 experts' partials.
__global__ void moe_reduce(const float* __restrict__ ws, float* __restrict__ out, int npts) {
    int p = blockIdx.x * 256 + threadIdx.x;
    if (p >= npts) return;
    float m = ws[p];
    #pragma unroll
    for (int e = 1; e < NE; ++e) m = fmaxf(m, ws[e * npts + p]);
    out[p] = m;
}

extern "C" void kernel_launch(void* const* d_in, const int* in_sizes, int n_in,
                              void* d_out, int out_size, void* d_ws, size_t ws_size,
                              hipStream_t stream) {
    const float* coords = (const float*)d_in[0];
    const float* W0 = (const float*)d_in[1];
    const float* b0 = (const float*)d_in[2];
    const float* W1 = (const float*)d_in[3];
    const float* b1 = (const float*)d_in[4];
    const float* W2 = (const float*)d_in[5];
    const float* b2 = (const float*)d_in[6];
    const float* W3 = (const float*)d_in[7];
    const float* b3 = (const float*)d_in[8];
    const int npts = in_sizes[0] / 3;

    unsigned short* W1p = (unsigned short*)d_ws;                   // 1 MB
    unsigned short* W2p = W1p + NE * 8 * SLICE_ELEMS;              // 1 MB
    unsigned short* W0k = W2p + NE * 8 * SLICE_ELEMS;              // 128 KB
    float* eout = (float*)(W0k + NE * SLICE_ELEMS);                // 3.2 MB

    const int PREP_TOT = NE * 8 * SLICE_ELEMS;
    prep_weights<<<(PREP_TOT + 255) / 256, 256, 0, stream>>>(W1, W2, W1p, W2p);
    prep_w0<<<(NE * HD + 255) / 256, 256, 0, stream>>>(W0, b0, W0k);

    int ntiles = (npts + NT - 1) / NT;
    moe_expert<<<ntiles * NE, NTHREADS, 0, stream>>>(
        coords, npts, W0k, b1, W1p, W2p, b2, W3, b3, eout);

    moe_reduce<<<(npts + 255) / 256, 256, 0, stream>>>(eout, (float*)d_out, npts);
}

// Round 22
// 244.213 us; speedup vs baseline: 1.5600x; 1.1166x over previous
//
#include <hip/hip_runtime.h>
#include <hip/hip_bf16.h>

#define NE 8
#define HD 256
#define NT 64
#define NTHREADS 256
#define WPITCH 32                      // af start-banks uniform; no pad needed
#define SLICE_ELEMS (HD * WPITCH)      // 8192 elems = 16384 B per K-slice

typedef __attribute__((ext_vector_type(8))) short short8;
typedef __attribute__((ext_vector_type(4))) float f32x4;

__device__ __forceinline__ unsigned short f2bf_u16(float f) {
    union { __hip_bfloat16 b; unsigned short u; } v;
    v.b = __float2bfloat16(f);          // HW RNE convert
    return v.u;
}
__device__ __forceinline__ unsigned int pack2bf(float lo, float hi) {
    return (unsigned int)f2bf_u16(lo) | ((unsigned int)f2bf_u16(hi) << 16);
}
// hi/lo bf16 split: v ≈ hi + lo with |v - hi - lo| <= 2^-16 |v|.
__device__ __forceinline__ void bfsplit(float v, unsigned short& hi, unsigned short& lo) {
    hi = f2bf_u16(v);
    union { unsigned int u; float f; } c; c.u = ((unsigned int)hi) << 16;
    lo = f2bf_u16(v - c.f);
}
// Act LDS swizzle (element units), proven in R12/R17.
__device__ __forceinline__ int swz(int row, int col) {
    return row * HD + (col ^ ((row & 7) << 3));
}

// Weights pre-swizzled: Wp[e][slice s][n][32], [n][kk] = W[k=s*32+kk][n].
__global__ void prep_weights(const float* __restrict__ W1, const float* __restrict__ W2,
                             unsigned short* __restrict__ W1p, unsigned short* __restrict__ W2p) {
    int idx = blockIdx.x * blockDim.x + threadIdx.x;
    const int TOT = NE * 8 * SLICE_ELEMS;
    if (idx >= TOT) return;
    int kk = idx & 31;
    int n  = (idx >> 5) & 255;
    int s  = (idx >> 13) & 7;
    int e  = idx >> 16;
    int k = s * 32 + kk;
    W1p[idx] = f2bf_u16(W1[(e * HD + k) * HD + n]);
    W2p[idx] = f2bf_u16(W2[(e * HD + k) * HD + n]);
}

// Layer-0 as a K=32 MFMA slice (bias folded in; pairs with cbufK B-slots).
__global__ void prep_w0(const float* __restrict__ W0, const float* __restrict__ b0,
                        unsigned short* __restrict__ W0k) {
    int idx = blockIdx.x * blockDim.x + threadIdx.x;   // e*HD + n
    if (idx >= NE * HD) return;
    int n = idx & 255, e = idx >> 8;
    float wx = W0[(e*3+0)*HD + n], wy = W0[(e*3+1)*HD + n], wz = W0[(e*3+2)*HD + n];
    float bb = b0[e*HD + n];
    unsigned short xh,xl,yh,yl,zh,zl,bh,bl;
    bfsplit(wx,xh,xl); bfsplit(wy,yh,yl); bfsplit(wz,zh,zl); bfsplit(bb,bh,bl);
    unsigned short s[32] = {xh,xh,xl, yh,yh,yl, zh,zh,zl, bh,bl};  // rest zero
    unsigned short* dst = W0k + idx * 32;
    #pragma unroll
    for (int i = 0; i < 32; ++i) dst[i] = s[i];
}

// Async stage one K-slice QUARTER (neuron rows [g*64,+64), 4 KB) — every wave
// stages its own quarter. Completion via __syncthreads (full vmcnt drain).
__device__ __forceinline__ void stage_slice(const unsigned short* __restrict__ gsrc,
                                            unsigned short* lbase, int g, int lane) {
    const char* gp = (const char*)gsrc + g * 4096 + lane * 16;
    char* l = (char*)lbase + g * 4096;
    #pragma unroll
    for (int i = 0; i < 4; ++i)
        __builtin_amdgcn_global_load_lds(
            (const __attribute__((address_space(1))) unsigned int*)(gp + i * 1024),
            (__attribute__((address_space(3))) unsigned int*)(l + i * 1024),
            16, 0, 0);
}

// One K-slice: 4 af (own neuron quarter) x 4 bf (all 64 points) -> 16 MFMA.
// Square 64x64 wave tile: 8 frag-reads per 256 KFLOP (vs 6 per 128 in R21).
#define KSLICE_BODY(CURBUF, K0)                                                              \
    {                                                                                        \
        const unsigned short* Ar = (CURBUF) + (g*64 + l15) * WPITCH + kg*8;                  \
        short8 af0 = *(const short8*)(Ar + 0*16*WPITCH);                                     \
        short8 af1 = *(const short8*)(Ar + 1*16*WPITCH);                                     \
        short8 af2 = *(const short8*)(Ar + 2*16*WPITCH);                                     \
        short8 af3 = *(const short8*)(Ar + 3*16*WPITCH);                                     \
        const int k0 = (K0) + kg*8;                                                          \
        _Pragma("unroll")                                                                    \
        for (int nt = 0; nt < 4; ++nt) {                                                     \
            short8 bf = *(const short8*)(Act + swz(nt*16 + l15, k0));                        \
            acc[0][nt] = __builtin_amdgcn_mfma_f32_16x16x32_bf16(af0, bf, acc[0][nt], 0,0,0);\
            acc[1][nt] = __builtin_amdgcn_mfma_f32_16x16x32_bf16(af1, bf, acc[1][nt], 0,0,0);\
            acc[2][nt] = __builtin_amdgcn_mfma_f32_16x16x32_bf16(af2, bf, acc[2][nt], 0,0,0);\
            acc[3][nt] = __builtin_amdgcn_mfma_f32_16x16x32_bf16(af3, bf, acc[3][nt], 0,0,0);\
        }                                                                                    \
    }

#define ACC_CLEAR()                                           \
    _Pragma("unroll")                                         \
    for (int mt = 0; mt < 4; ++mt)                            \
        _Pragma("unroll")                                     \
        for (int nt = 0; nt < 4; ++nt)                        \
            acc[mt][nt] = (f32x4){0.f, 0.f, 0.f, 0.f};

// One expert per block: blockIdx = tile*8 + e. 4 waves, wave g owns neurons
// [g*64,+64) x ALL 64 points. Single Wb buffer -> 52 KB LDS -> 3 blocks/CU.
__global__ __launch_bounds__(NTHREADS, 3) void moe_expert(
    const float* __restrict__ coords, int npts,
    const unsigned short* __restrict__ W0k, const float* __restrict__ b1,
    const unsigned short* __restrict__ W1p,
    const unsigned short* __restrict__ W2p, const float* __restrict__ b2,
    const float* __restrict__ W3, const float* __restrict__ b3,
    float* __restrict__ ws)
{
    __shared__ __align__(16) unsigned short Act[NT * HD];      // 32 KB
    __shared__ __align__(16) unsigned short Wb[SLICE_ELEMS];   // 16 KB (single buf)
    __shared__ __align__(16) unsigned char aux[NT * 32 * 2];   // 4 KB: cbufK / pscr
    unsigned short* cbufK = (unsigned short*)aux;   // phase 0-1 only
    float* pscr = (float*)aux;                      // tail only (disjoint in time)

    const int t = threadIdx.x;
    const int lane = t & 63;
    const int g = t >> 6;       // 0..3: neuron group of 64
    const int l15 = lane & 15;
    const int kg = lane >> 4;
    const int e = blockIdx.x & 7;
    const int p0 = (blockIdx.x >> 3) * NT;

    const unsigned short* W0e = W0k + e * SLICE_ELEMS;
    const unsigned short* W1e = W1p + e * 8 * SLICE_ELEMS;
    const unsigned short* W2e = W2p + e * 8 * SLICE_ELEMS;

    // ---- phase 0: stage W0k slice; build per-point B-slots (hi/lo split) ----
    stage_slice(W0e, Wb, g, lane);
    if (t < NT) {
        int p = p0 + t;
        int pc = p < npts ? p : npts - 1;      // clamp; store masked later
        float x = coords[pc*3], y = coords[pc*3+1], z = coords[pc*3+2];
        unsigned short xh,xl,yh,yl,zh,zl;
        bfsplit(x,xh,xl); bfsplit(y,yh,yl); bfsplit(z,zh,zl);
        const unsigned short ONE = 0x3F80;     // bf16(1.0)
        union { unsigned short s[32]; uint4 q[4]; } pk;
        #pragma unroll
        for (int i = 0; i < 32; ++i) pk.s[i] = 0;
        pk.s[0]=xh; pk.s[1]=xl; pk.s[2]=xh;
        pk.s[3]=yh; pk.s[4]=yl; pk.s[5]=yh;
        pk.s[6]=zh; pk.s[7]=zl; pk.s[8]=zh;
        pk.s[9]=ONE; pk.s[10]=ONE;
        uint4* dst = (uint4*)(cbufK + t * 32);
        dst[0]=pk.q[0]; dst[1]=pk.q[1]; dst[2]=pk.q[2]; dst[3]=pk.q[3];
    }
    f32x4 b1v[4];
    #pragma unroll
    for (int mt = 0; mt < 4; ++mt)
        b1v[mt] = *(const f32x4*)(b1 + e*HD + g*64 + mt*16 + kg*4);
    __syncthreads();                    // cbufK visible + W0k staged

    f32x4 acc[4][4];
    ACC_CLEAR()

    // ---- phase 1: L0 as one MFMA K-slice (bias in slots) -> Act ----
    {
        const unsigned short* Ar = Wb + (g*64 + l15) * WPITCH + kg*8;
        short8 af0 = *(const short8*)(Ar + 0*16*WPITCH);
        short8 af1 = *(const short8*)(Ar + 1*16*WPITCH);
        short8 af2 = *(const short8*)(Ar + 2*16*WPITCH);
        short8 af3 = *(const short8*)(Ar + 3*16*WPITCH);
        #pragma unroll
        for (int nt = 0; nt < 4; ++nt) {
            short8 bf = *(const short8*)(cbufK + (nt*16 + l15) * 32 + kg*8);
            acc[0][nt] = __builtin_amdgcn_mfma_f32_16x16x32_bf16(af0, bf, acc[0][nt], 0,0,0);
            acc[1][nt] = __builtin_amdgcn_mfma_f32_16x16x32_bf16(af1, bf, acc[1][nt], 0,0,0);
            acc[2][nt] = __builtin_amdgcn_mfma_f32_16x16x32_bf16(af2, bf, acc[2][nt], 0,0,0);
            acc[3][nt] = __builtin_amdgcn_mfma_f32_16x16x32_bf16(af3, bf, acc[3][nt], 0,0,0);
        }
        #pragma unroll
        for (int mt = 0; mt < 4; ++mt)
            #pragma unroll
            for (int nt = 0; nt < 4; ++nt) {
                const int p = nt*16 + l15;
                const int n0 = g*64 + mt*16 + kg*4;
                unsigned int lo = pack2bf(fmaxf(acc[mt][nt][0], 0.f),
                                          fmaxf(acc[mt][nt][1], 0.f));
                unsigned int hi = pack2bf(fmaxf(acc[mt][nt][2], 0.f),
                                          fmaxf(acc[mt][nt][3], 0.f));
                *(uint2*)(Act + swz(p, n0)) = make_uint2(lo, hi);
            }
    }
    __syncthreads();                    // Act ready; all Wb(W0k) reads done
    stage_slice(W1e, Wb, g, lane);      // stage L1 s0
    __syncthreads();                    // drained

    ACC_CLEAR()
    // ---- layer 1: 8 K-slices, single buffer, 2 barriers/slice ----
    #pragma unroll
    for (int s = 0; s < 8; ++s) {
        KSLICE_BODY(Wb, s*32)
        __syncthreads();                // Wb reads done
        if (s < 7) {
            stage_slice(W1e + (s+1) * SLICE_ELEMS, Wb, g, lane);
            __syncthreads();            // drained
        }
    }
    stage_slice(W2e, Wb, g, lane);      // stage L2 s0 (drain hides under epilogue)
    // ---- layer-1 epilogue: bias+relu -> Act in place ----
    #pragma unroll
    for (int mt = 0; mt < 4; ++mt) {
        const int n0 = g*64 + mt*16 + kg*4;
        const f32x4 bb = b1v[mt];
        #pragma unroll
        for (int nt = 0; nt < 4; ++nt) {
            const int p = nt*16 + l15;
            unsigned int lo = pack2bf(fmaxf(acc[mt][nt][0] + bb[0], 0.f),
                                      fmaxf(acc[mt][nt][1] + bb[1], 0.f));
            unsigned int hi = pack2bf(fmaxf(acc[mt][nt][2] + bb[2], 0.f),
                                      fmaxf(acc[mt][nt][3] + bb[3], 0.f));
            *(uint2*)(Act + swz(p, n0)) = make_uint2(lo, hi);
        }
    }
    __syncthreads();                    // Act W->R + L2 s0 staged (drain)

    ACC_CLEAR()
    // ---- layer 2: 8 K-slices ----
    #pragma unroll
    for (int s = 0; s < 8; ++s) {
        KSLICE_BODY(Wb, s*32)
        if (s < 7) {
            __syncthreads();            // Wb reads done
            stage_slice(W2e + (s+1) * SLICE_ELEMS, Wb, g, lane);
            __syncthreads();            // drained
        }
    }

    // ---- fused layer-2 epilogue + layer 3 (fp32, in registers) ----
    {
        f32x4 bbv[4], w3v[4];
        #pragma unroll
        for (int mt = 0; mt < 4; ++mt) {
            const int nb = g*64 + mt*16 + kg*4;
            bbv[mt] = *(const f32x4*)(b2 + e*HD + nb);
            w3v[mt] = *(const f32x4*)(W3 + e*HD + nb);
        }
        __syncthreads();                // all cbufK use long past; pscr aliasing safe
        #pragma unroll
        for (int nt = 0; nt < 4; ++nt) {
            float s = 0.f;
            #pragma unroll
            for (int mt = 0; mt < 4; ++mt)
                #pragma unroll
                for (int r = 0; r < 4; ++r)
                    s += fmaxf(acc[mt][nt][r] + bbv[mt][r], 0.f) * w3v[mt][r];
            s += __shfl_xor(s, 16);   // reduce over kg (4 lanes per point)
            s += __shfl_xor(s, 32);
            if (kg == 0) pscr[(nt*16 + l15) * 4 + g] = s;
        }
    }
    __syncthreads();                    // pscr W->R boundary
    if (t < NT) {
        f32x4 v = *(const f32x4*)(pscr + t * 4);
        int p = p0 + t;
        if (p < npts) ws[e * npts + p] = v[0] + v[1] + v[2] + v[3] + b3[e];
    }
}

// Max over the 8 experts' partials.
__global__ void moe_reduce(const float* __restrict__ ws, float* __restrict__ out, int npts) {
    int p = blockIdx.x * 256 + threadIdx.x;
    if (p >= npts) return;
    float m = ws[p];
    #pragma unroll
    for (int e = 1; e < NE; ++e) m = fmaxf(m, ws[e * npts + p]);
    out[p] = m;
}

extern "C" void kernel_launch(void* const* d_in, const int* in_sizes, int n_in,
                              void* d_out, int out_size, void* d_ws, size_t ws_size,
                              hipStream_t stream) {
    const float* coords = (const float*)d_in[0];
    const float* W0 = (const float*)d_in[1];
    const float* b0 = (const float*)d_in[2];
    const float* W1 = (const float*)d_in[3];
    const float* b1 = (const float*)d_in[4];
    const float* W2 = (const float*)d_in[5];
    const float* b2 = (const float*)d_in[6];
    const float* W3 = (const float*)d_in[7];
    const float* b3 = (const float*)d_in[8];
    const int npts = in_sizes[0] / 3;

    unsigned short* W1p = (unsigned short*)d_ws;                   // 1 MB
    unsigned short* W2p = W1p + NE * 8 * SLICE_ELEMS;              // 1 MB
    unsigned short* W0k = W2p + NE * 8 * SLICE_ELEMS;              // 128 KB
    float* eout = (float*)(W0k + NE * SLICE_ELEMS);                // 3.2 MB

    const int PREP_TOT = NE * 8 * SLICE_ELEMS;
    prep_weights<<<(PREP_TOT + 255) / 256, 256, 0, stream>>>(W1, W2, W1p, W2p);
    prep_w0<<<(NE * HD + 255) / 256, 256, 0, stream>>>(W0, b0, W0k);

    int ntiles = (npts + NT - 1) / NT;
    moe_expert<<<ntiles * NE, NTHREADS, 0, stream>>>(
        coords, npts, W0k, b1, W1p, W2p, b2, W3, b3, eout);

    moe_reduce<<<(npts + 255) / 256, 256, 0, stream>>>(eout, (float*)d_out, npts);
}